// Round 1
// baseline (548.349 us; speedup 1.0000x reference)
//
#include <hip/hip_runtime.h>

typedef unsigned short u16;
typedef __bf16 bf16x8 __attribute__((ext_vector_type(8)));
typedef float f32x4 __attribute__((ext_vector_type(4)));
typedef u16 u16x8 __attribute__((ext_vector_type(8)));

union B8 { u16x8 u; bf16x8 b; };

__device__ __forceinline__ u16 f2b(float f){
  unsigned u = __float_as_uint(f);
  return (u16)((u + 0x7FFFu + ((u >> 16) & 1u)) >> 16);
}
__device__ __forceinline__ float b2f(u16 h){ return __uint_as_float(((unsigned)h) << 16); }

// ---------------- split fp32 -> bf16 hi (+ optional lo) ----------------
__global__ __launch_bounds__(256) void split4_kernel(const float* __restrict__ x,
    u16* __restrict__ hi, u16* __restrict__ lo, long n4){
  long i = (long)blockIdx.x * 256 + threadIdx.x;
  if (i >= n4) return;
  float4 v = ((const float4*)x)[i];
  ushort4 h;
  h.x = f2b(v.x); h.y = f2b(v.y); h.z = f2b(v.z); h.w = f2b(v.w);
  ((ushort4*)hi)[i] = h;
  if (lo){
    ushort4 l;
    l.x = f2b(v.x - b2f(h.x)); l.y = f2b(v.y - b2f(h.y));
    l.z = f2b(v.z - b2f(h.z)); l.w = f2b(v.w - b2f(h.w));
    ((ushort4*)lo)[i] = l;
  }
}

// ---------------- NT GEMM: C[m][n] = sum_k A[m][k] * B[n][k] ----------------
// DUAL: A,B given as hi/lo bf16 pairs; acc = Ah*Bh + Ah*Bl + Al*Bh  (fp32-class)
// EPI: 0 = +bias, split C into hi/lo bf16 row-major
//      1 = +bias, write bf16 transposed per-batch: out[(m/seq)][n][m%seq]
//      2 = write fp32 C (batched by sOb)
//      3 = + residual, write fp32 C (batched)
constexpr int BM = 128, BN = 128, BK = 32, PAD = 8, LDK = BK + PAD;  // LDK*2B = 80B: 16B-aligned, conflict-benign

template<bool DUAL, int EPI>
__global__ __launch_bounds__(256, 2)
void gemm_nt(const u16* __restrict__ Ahi, const u16* __restrict__ Alo,
             const u16* __restrict__ Bhi, const u16* __restrict__ Blo,
             const float* __restrict__ bias, const float* __restrict__ residual,
             void* __restrict__ out0, void* __restrict__ out1,
             int M, int N, int K,
             long sAb, long sBb, long sOb, long sRb, int seq)
{
  constexpr int NARR = DUAL ? 4 : 2;
  __shared__ u16 lds[NARR][BM * LDK];

  const int t = threadIdx.x;
  const int bz = blockIdx.z;
  const int tileM = blockIdx.y * BM;
  const int tileN = blockIdx.x * BN;

  const u16* gsrc[NARR];
  gsrc[0] = Ahi + (long)bz * sAb + (long)tileM * K;
  gsrc[1] = Bhi + (long)bz * sBb + (long)tileN * K;
  if (DUAL){
    gsrc[2] = Alo + (long)bz * sAb + (long)tileM * K;
    gsrc[3] = Blo + (long)bz * sBb + (long)tileN * K;
  }

  const int wave = t >> 6, lane = t & 63;
  const int wm = (wave >> 1) * 64, wn = (wave & 1) * 64;
  const int lr = lane & 15;          // A-row / B-col within 16x16 tile
  const int lk = (lane >> 4) * 8;    // k offset of 8-elem fragment

  f32x4 acc[4][4] = {};

  for (int k0 = 0; k0 < K; k0 += BK){
    __syncthreads();
    #pragma unroll
    for (int arr = 0; arr < NARR; arr++){
      #pragma unroll
      for (int i = 0; i < 2; i++){
        int seg = t + i * 256;
        int row = seg >> 2, kk = (seg & 3) * 8;
        *(u16x8*)&lds[arr][row * LDK + kk] =
            *(const u16x8*)(gsrc[arr] + (long)row * K + k0 + kk);
      }
    }
    __syncthreads();

    B8 af[DUAL ? 2 : 1][4], bfr[DUAL ? 2 : 1][4];
    #pragma unroll
    for (int mt = 0; mt < 4; mt++){
      af[0][mt].u = *(const u16x8*)&lds[0][(wm + mt*16 + lr) * LDK + lk];
      if (DUAL) af[1][mt].u = *(const u16x8*)&lds[2][(wm + mt*16 + lr) * LDK + lk];
    }
    #pragma unroll
    for (int nt = 0; nt < 4; nt++){
      bfr[0][nt].u = *(const u16x8*)&lds[1][(wn + nt*16 + lr) * LDK + lk];
      if (DUAL) bfr[1][nt].u = *(const u16x8*)&lds[3][(wn + nt*16 + lr) * LDK + lk];
    }
    #pragma unroll
    for (int mt = 0; mt < 4; mt++){
      #pragma unroll
      for (int nt = 0; nt < 4; nt++){
        acc[mt][nt] = __builtin_amdgcn_mfma_f32_16x16x32_bf16(af[0][mt].b, bfr[0][nt].b, acc[mt][nt], 0, 0, 0);
        if (DUAL){
          acc[mt][nt] = __builtin_amdgcn_mfma_f32_16x16x32_bf16(af[0][mt].b, bfr[1][nt].b, acc[mt][nt], 0, 0, 0);
          acc[mt][nt] = __builtin_amdgcn_mfma_f32_16x16x32_bf16(af[1][mt].b, bfr[0][nt].b, acc[mt][nt], 0, 0, 0);
        }
      }
    }
  }

  // epilogue: C/D layout col=lane&15, row=(lane>>4)*4+reg  [m89-verified]
  const int rq = (lane >> 4) * 4;
  #pragma unroll
  for (int nt = 0; nt < 4; nt++){
    const int n = tileN + wn + nt*16 + lr;
    const float bv = (EPI <= 1) ? bias[n] : 0.f;
    #pragma unroll
    for (int mt = 0; mt < 4; mt++){
      #pragma unroll
      for (int r = 0; r < 4; r++){
        const int m = tileM + wm + mt*16 + rq + r;
        float val = acc[mt][nt][r] + bv;
        if (EPI == 0){
          u16 h = f2b(val);
          ((u16*)out0)[(long)m * N + n] = h;
          ((u16*)out1)[(long)m * N + n] = f2b(val - b2f(h));
        } else if (EPI == 1){
          long idx = (long)(m / seq) * ((long)N * seq) + (long)n * seq + (m % seq);
          ((u16*)out0)[idx] = f2b(val);
        } else if (EPI == 2){
          ((float*)out0)[(long)bz * sOb + (long)m * N + n] = val;
        } else {
          float res = residual[(long)bz * sRb + (long)m * N + n];
          ((float*)out0)[(long)bz * sOb + (long)m * N + n] = val + res;
        }
      }
    }
  }
}

// ---------------- row softmax: fp32 scores -> bf16 probs (n == 2048) ----------------
__global__ __launch_bounds__(256)
void softmax_kernel(const float* __restrict__ S, u16* __restrict__ P, int n){
  const long row = blockIdx.x;
  const float* r = S + row * (long)n;
  const int t = threadIdx.x;
  float v[8];
  float mx = -3.0e38f;
  #pragma unroll
  for (int i = 0; i < 8; i++){ v[i] = r[t + (i << 8)]; mx = fmaxf(mx, v[i]); }
  #pragma unroll
  for (int off = 32; off > 0; off >>= 1) mx = fmaxf(mx, __shfl_xor(mx, off, 64));
  __shared__ float red[8];
  const int wave = t >> 6;
  if ((t & 63) == 0) red[wave] = mx;
  __syncthreads();
  mx = fmaxf(fmaxf(red[0], red[1]), fmaxf(red[2], red[3]));
  float s = 0.f;
  #pragma unroll
  for (int i = 0; i < 8; i++){ v[i] = __expf(v[i] - mx); s += v[i]; }
  #pragma unroll
  for (int off = 32; off > 0; off >>= 1) s += __shfl_xor(s, off, 64);
  if ((t & 63) == 0) red[4 + wave] = s;
  __syncthreads();
  s = red[4] + red[5] + red[6] + red[7];
  const float inv = 1.f / s;
  u16* pr = P + row * (long)n;
  #pragma unroll
  for (int i = 0; i < 8; i++) pr[t + (i << 8)] = f2b(v[i] * inv);
}

extern "C" void kernel_launch(void* const* d_in, const int* in_sizes, int n_in,
                              void* d_out, int out_size, void* d_ws, size_t ws_size,
                              hipStream_t stream){
  (void)in_sizes; (void)n_in; (void)out_size; (void)ws_size;
  const float* q  = (const float*)d_in[0];
  const float* k  = (const float*)d_in[1];
  const float* v  = (const float*)d_in[2];
  const float* Wq = (const float*)d_in[3];
  const float* bq = (const float*)d_in[4];
  const float* Wk = (const float*)d_in[5];
  const float* bk = (const float*)d_in[6];
  const float* Wv = (const float*)d_in[7];
  const float* bv = (const float*)d_in[8];
  float* out = (float*)d_out;

  const int B = 4, S = 2048, F = 1024;
  const long NSF = (long)B * S * F;   // 8 Mi elems
  const long NFF = (long)F * F;       // 1 Mi elems
  const long NSS = (long)B * S * S;   // 16 Mi elems

  char* w = (char*)d_ws;
  auto alloc = [&](long bytes) -> char* {
    char* p = w; w += (bytes + 255) & ~(long)255; return p;
  };
  // persistent (needed through the whole pipeline): ~80 MB
  u16* qp_hi = (u16*)alloc(NSF * 2); u16* qp_lo = (u16*)alloc(NSF * 2);
  u16* kp_hi = (u16*)alloc(NSF * 2); u16* kp_lo = (u16*)alloc(NSF * 2);
  u16* vpT   = (u16*)alloc(NSF * 2);
  // zone2: phase-1 split inputs (dead after projections), re-used for scores/attn
  char* zone2 = w;
  u16* q_hi = (u16*)alloc(NSF * 2); u16* q_lo = (u16*)alloc(NSF * 2);
  u16* k_hi = (u16*)alloc(NSF * 2); u16* k_lo = (u16*)alloc(NSF * 2);
  u16* v_b  = (u16*)alloc(NSF * 2);
  u16* Wq_hi = (u16*)alloc(NFF * 2); u16* Wq_lo = (u16*)alloc(NFF * 2);
  u16* Wk_hi = (u16*)alloc(NFF * 2); u16* Wk_lo = (u16*)alloc(NFF * 2);
  u16* Wv_b  = (u16*)alloc(NFF * 2);
  // phase-2 aliases zone2 (projection inputs are dead by then)
  float* scores = (float*)zone2;             // NSS * 4 = 67 MB
  u16*   attn   = (u16*)(zone2 + NSS * 4);   // NSS * 2 = 33.5 MB

  dim3 blk(256);
  long n4 = NSF / 4, m4 = NFF / 4;
  split4_kernel<<<dim3((unsigned)(n4 / 256)), blk, 0, stream>>>(q, q_hi, q_lo, n4);
  split4_kernel<<<dim3((unsigned)(n4 / 256)), blk, 0, stream>>>(k, k_hi, k_lo, n4);
  split4_kernel<<<dim3((unsigned)(n4 / 256)), blk, 0, stream>>>(v, v_b, nullptr, n4);
  split4_kernel<<<dim3((unsigned)(m4 / 256)), blk, 0, stream>>>(Wq, Wq_hi, Wq_lo, m4);
  split4_kernel<<<dim3((unsigned)(m4 / 256)), blk, 0, stream>>>(Wk, Wk_hi, Wk_lo, m4);
  split4_kernel<<<dim3((unsigned)(m4 / 256)), blk, 0, stream>>>(Wv, Wv_b, nullptr, m4);

  // qp = q @ Wq^T + bq  (split-precision), stored as hi/lo bf16
  gemm_nt<true, 0><<<dim3(F / BN, (B * S) / BM, 1), blk, 0, stream>>>(
      q_hi, q_lo, Wq_hi, Wq_lo, bq, nullptr, qp_hi, qp_lo,
      B * S, F, F, 0, 0, 0, 0, S);
  gemm_nt<true, 0><<<dim3(F / BN, (B * S) / BM, 1), blk, 0, stream>>>(
      k_hi, k_lo, Wk_hi, Wk_lo, bk, nullptr, kp_hi, kp_lo,
      B * S, F, F, 0, 0, 0, 0, S);
  // vp = v @ Wv^T + bv, written transposed per batch: vpT[b][g][s]
  gemm_nt<false, 1><<<dim3(F / BN, (B * S) / BM, 1), blk, 0, stream>>>(
      v_b, nullptr, Wv_b, nullptr, bv, nullptr, vpT, nullptr,
      B * S, F, F, 0, 0, 0, 0, S);
  // scores[b] = qp[b] @ kp[b]^T  (split-precision, fp32 out)
  gemm_nt<true, 2><<<dim3(S / BN, S / BM, B), blk, 0, stream>>>(
      qp_hi, qp_lo, kp_hi, kp_lo, nullptr, nullptr, scores, nullptr,
      S, S, F, (long)S * F, (long)S * F, (long)S * S, 0, S);
  // attn = softmax(scores) as bf16
  softmax_kernel<<<dim3(B * S), blk, 0, stream>>>(scores, attn, S);
  // out[b] = attn[b] @ vp[b] + q[b]
  gemm_nt<false, 3><<<dim3(F / BN, S / BM, B), blk, 0, stream>>>(
      attn, nullptr, vpT, nullptr, nullptr, q, out, nullptr,
      S, F, S, (long)S * S, (long)F * S, (long)S * F, (long)S * F, S);
}

// Round 2
// 522.836 us; speedup vs baseline: 1.0488x; 1.0488x over previous
//
#include <hip/hip_runtime.h>

typedef unsigned short u16;
typedef __bf16 bf16x8 __attribute__((ext_vector_type(8)));
typedef float f32x4 __attribute__((ext_vector_type(4)));
typedef u16 u16x8 __attribute__((ext_vector_type(8)));

union B8 { u16x8 u; bf16x8 b; };

__device__ __forceinline__ u16 f2b(float f){
  unsigned u = __float_as_uint(f);
  return (u16)((u + 0x7FFFu + ((u >> 16) & 1u)) >> 16);
}
__device__ __forceinline__ float b2f(u16 h){ return __uint_as_float(((unsigned)h) << 16); }

// ---------------- fused split: all six tensors in one launch ----------------
// block ranges (256 thr, float4 per thr): q[0,8192) k[8192,16384) v[16384,24576)
// Wq[24576,25600) Wk[25600,26624) Wv[26624,27648)
__global__ __launch_bounds__(256) void split_all_kernel(
    const float* __restrict__ q, const float* __restrict__ k, const float* __restrict__ v,
    const float* __restrict__ Wq, const float* __restrict__ Wk, const float* __restrict__ Wv,
    u16* __restrict__ q_hi, u16* __restrict__ q_lo,
    u16* __restrict__ k_hi, u16* __restrict__ k_lo, u16* __restrict__ v_b,
    u16* __restrict__ Wq_hi, u16* __restrict__ Wq_lo,
    u16* __restrict__ Wk_hi, u16* __restrict__ Wk_lo, u16* __restrict__ Wv_b)
{
  int b = blockIdx.x;
  const float* src; u16* hi; u16* lo = nullptr; long base;
  if      (b < 8192)  { src = q;  hi = q_hi;  lo = q_lo;  base = b; }
  else if (b < 16384) { src = k;  hi = k_hi;  lo = k_lo;  base = b - 8192; }
  else if (b < 24576) { src = v;  hi = v_b;               base = b - 16384; }
  else if (b < 25600) { src = Wq; hi = Wq_hi; lo = Wq_lo; base = b - 24576; }
  else if (b < 26624) { src = Wk; hi = Wk_hi; lo = Wk_lo; base = b - 25600; }
  else                { src = Wv; hi = Wv_b;              base = b - 26624; }
  long i = base * 256 + threadIdx.x;
  float4 x = ((const float4*)src)[i];
  ushort4 h;
  h.x = f2b(x.x); h.y = f2b(x.y); h.z = f2b(x.z); h.w = f2b(x.w);
  ((ushort4*)hi)[i] = h;
  if (lo){
    ushort4 l;
    l.x = f2b(x.x - b2f(h.x)); l.y = f2b(x.y - b2f(h.y));
    l.z = f2b(x.z - b2f(h.z)); l.w = f2b(x.w - b2f(h.w));
    ((ushort4*)lo)[i] = l;
  }
}

// ---------------- NT GEMM: C[m][n] = sum_k A[m][k] * B[n][k] ----------------
// DUAL: A,B given as hi/lo bf16 pairs; acc = Ah*Bh + Ah*Bl + Al*Bh  (fp32-class)
// EPI: 0 = +bias(z-select), split C into hi/lo bf16 row-major, batched by sOb
//      1 = +bias, write bf16 transposed per-batch: out[(m/seq)][n][m%seq]
//      2 = write fp32 C (batched by sOb)
//      3 = + residual, write fp32 C (batched)
// LDS layout: no pad. Row = 32 u16 = 64B = 4 groups of 16B; group g of row stored
// at slot (g + (row>>1)) & 3. Reads & writes both resolve to 2-way bank phases
// (free per m136); all accesses 16B-aligned so ds_*_b128 is emitted.
constexpr int BM = 128, BN = 128, BK = 32;

__device__ __forceinline__ int lds_idx(int row, int g){
  return row * BK + (((g + (row >> 1)) & 3) << 3);
}

template<bool DUAL, int EPI>
__global__ __launch_bounds__(256, 4)   // 4 blocks/CU: LDS 32KB(dual) x4 = 128KB <= 160KB
void gemm_nt(const u16* __restrict__ Ahi, const u16* __restrict__ Alo,
             const u16* __restrict__ Bhi, const u16* __restrict__ Blo,
             const float* __restrict__ bias, const float* __restrict__ biasB,
             const float* __restrict__ residual,
             void* __restrict__ out0, void* __restrict__ out1,
             int M, int N, int K,
             long sAb, long sBb, long sOb, long sRb, int seq)
{
  constexpr int NARR = DUAL ? 4 : 2;
  __shared__ u16 lds[NARR][BM * BK];

  const int t = threadIdx.x;
  const int bz = blockIdx.z;
  const int tileM = blockIdx.y * BM;
  const int tileN = blockIdx.x * BN;

  const u16* gsrc[NARR];
  gsrc[0] = Ahi + (long)bz * sAb + (long)tileM * K;
  gsrc[1] = Bhi + (long)bz * sBb + (long)tileN * K;
  if (DUAL){
    gsrc[2] = Alo + (long)bz * sAb + (long)tileM * K;
    gsrc[3] = Blo + (long)bz * sBb + (long)tileN * K;
  }

  const int wave = t >> 6, lane = t & 63;
  const int wm = (wave >> 1) * 64, wn = (wave & 1) * 64;
  const int lr = lane & 15;          // A-row / B-col within 16x16 tile
  const int lg = lane >> 4;          // k-group (8 elems) of the fragment

  f32x4 acc[4][4] = {};

  for (int k0 = 0; k0 < K; k0 += BK){
    __syncthreads();
    #pragma unroll
    for (int arr = 0; arr < NARR; arr++){
      #pragma unroll
      for (int i = 0; i < 2; i++){
        int seg = t + i * 256;
        int row = seg >> 2, g = seg & 3;
        *(u16x8*)&lds[arr][lds_idx(row, g)] =
            *(const u16x8*)(gsrc[arr] + (long)row * K + k0 + g * 8);
      }
    }
    __syncthreads();

    B8 af[DUAL ? 2 : 1][4], bfr[DUAL ? 2 : 1][4];
    #pragma unroll
    for (int mt = 0; mt < 4; mt++){
      af[0][mt].u = *(const u16x8*)&lds[0][lds_idx(wm + mt*16 + lr, lg)];
      if (DUAL) af[1][mt].u = *(const u16x8*)&lds[2][lds_idx(wm + mt*16 + lr, lg)];
    }
    #pragma unroll
    for (int nt = 0; nt < 4; nt++){
      bfr[0][nt].u = *(const u16x8*)&lds[1][lds_idx(wn + nt*16 + lr, lg)];
      if (DUAL) bfr[1][nt].u = *(const u16x8*)&lds[3][lds_idx(wn + nt*16 + lr, lg)];
    }
    #pragma unroll
    for (int mt = 0; mt < 4; mt++){
      #pragma unroll
      for (int nt = 0; nt < 4; nt++){
        acc[mt][nt] = __builtin_amdgcn_mfma_f32_16x16x32_bf16(af[0][mt].b, bfr[0][nt].b, acc[mt][nt], 0, 0, 0);
        if (DUAL){
          acc[mt][nt] = __builtin_amdgcn_mfma_f32_16x16x32_bf16(af[0][mt].b, bfr[1][nt].b, acc[mt][nt], 0, 0, 0);
          acc[mt][nt] = __builtin_amdgcn_mfma_f32_16x16x32_bf16(af[1][mt].b, bfr[0][nt].b, acc[mt][nt], 0, 0, 0);
        }
      }
    }
  }

  // epilogue: C/D layout col=lane&15, row=(lane>>4)*4+reg  [m89-verified]
  const int rq = (lane >> 4) * 4;
  const float* bp = (bz && biasB) ? biasB : bias;
  #pragma unroll
  for (int nt = 0; nt < 4; nt++){
    const int n = tileN + wn + nt*16 + lr;
    const float bv = (EPI <= 1) ? bp[n] : 0.f;
    #pragma unroll
    for (int mt = 0; mt < 4; mt++){
      #pragma unroll
      for (int r = 0; r < 4; r++){
        const int m = tileM + wm + mt*16 + rq + r;
        float val = acc[mt][nt][r] + bv;
        if (EPI == 0){
          u16 h = f2b(val);
          ((u16*)out0)[(long)bz * sOb + (long)m * N + n] = h;
          ((u16*)out1)[(long)bz * sOb + (long)m * N + n] = f2b(val - b2f(h));
        } else if (EPI == 1){
          long idx = (long)(m / seq) * ((long)N * seq) + (long)n * seq + (m % seq);
          ((u16*)out0)[idx] = f2b(val);
        } else if (EPI == 2){
          ((float*)out0)[(long)bz * sOb + (long)m * N + n] = val;
        } else {
          float res = residual[(long)bz * sRb + (long)m * N + n];
          ((float*)out0)[(long)bz * sOb + (long)m * N + n] = val + res;
        }
      }
    }
  }
}

// ---------------- row softmax: fp32 scores -> bf16 probs (n == 2048) ----------------
__global__ __launch_bounds__(256)
void softmax_kernel(const float* __restrict__ S, u16* __restrict__ P, int n){
  const long row = blockIdx.x;
  const float* r = S + row * (long)n;
  const int t = threadIdx.x;
  float v[8];
  float mx = -3.0e38f;
  #pragma unroll
  for (int i = 0; i < 8; i++){ v[i] = r[t + (i << 8)]; mx = fmaxf(mx, v[i]); }
  #pragma unroll
  for (int off = 32; off > 0; off >>= 1) mx = fmaxf(mx, __shfl_xor(mx, off, 64));
  __shared__ float red[8];
  const int wave = t >> 6;
  if ((t & 63) == 0) red[wave] = mx;
  __syncthreads();
  mx = fmaxf(fmaxf(red[0], red[1]), fmaxf(red[2], red[3]));
  float s = 0.f;
  #pragma unroll
  for (int i = 0; i < 8; i++){ v[i] = __expf(v[i] - mx); s += v[i]; }
  #pragma unroll
  for (int off = 32; off > 0; off >>= 1) s += __shfl_xor(s, off, 64);
  if ((t & 63) == 0) red[4 + wave] = s;
  __syncthreads();
  s = red[4] + red[5] + red[6] + red[7];
  const float inv = 1.f / s;
  u16* pr = P + row * (long)n;
  #pragma unroll
  for (int i = 0; i < 8; i++) pr[t + (i << 8)] = f2b(v[i] * inv);
}

extern "C" void kernel_launch(void* const* d_in, const int* in_sizes, int n_in,
                              void* d_out, int out_size, void* d_ws, size_t ws_size,
                              hipStream_t stream){
  (void)in_sizes; (void)n_in; (void)out_size; (void)ws_size;
  const float* q  = (const float*)d_in[0];
  const float* k  = (const float*)d_in[1];
  const float* v  = (const float*)d_in[2];
  const float* Wq = (const float*)d_in[3];
  const float* bq = (const float*)d_in[4];
  const float* Wk = (const float*)d_in[5];
  const float* bk = (const float*)d_in[6];
  const float* Wv = (const float*)d_in[7];
  const float* bv = (const float*)d_in[8];
  float* out = (float*)d_out;

  const int B = 4, S = 2048, F = 1024;
  const long NSF = (long)B * S * F;   // 8 Mi elems
  const long NFF = (long)F * F;       // 1 Mi elems
  const long NSS = (long)B * S * S;   // 16 Mi elems

  char* w = (char*)d_ws;
  auto alloc = [&](long bytes) -> char* {
    char* p = w; w += (bytes + 255) & ~(long)255; return p;
  };
  // persistent: qp/kp hi pairs contiguous (batch-stride addressing), ~80 MB
  u16* qp_hi = (u16*)alloc(2 * NSF * 2); u16* kp_hi = qp_hi + NSF;
  u16* qp_lo = (u16*)alloc(2 * NSF * 2); u16* kp_lo = qp_lo + NSF;
  u16* vpT   = (u16*)alloc(NSF * 2);
  // zone2: phase-1 split inputs (dead after projections), re-used for scores/attn
  char* zone2 = w;
  u16* q_hi = (u16*)alloc(2 * NSF * 2); u16* k_hi = q_hi + NSF;   // contiguous z-pair
  u16* q_lo = (u16*)alloc(2 * NSF * 2); u16* k_lo = q_lo + NSF;
  u16* v_b  = (u16*)alloc(NSF * 2);
  u16* Wq_hi = (u16*)alloc(2 * NFF * 2); u16* Wk_hi = Wq_hi + NFF;
  u16* Wq_lo = (u16*)alloc(2 * NFF * 2); u16* Wk_lo = Wq_lo + NFF;
  u16* Wv_b  = (u16*)alloc(NFF * 2);
  // phase-2 aliases zone2 (projection inputs are dead by then)
  float* scores = (float*)zone2;             // NSS * 4 = 67 MB
  u16*   attn   = (u16*)(zone2 + NSS * 4);   // NSS * 2 = 33.5 MB

  dim3 blk(256);

  // 1) split all six inputs in one launch
  split_all_kernel<<<dim3(27648), blk, 0, stream>>>(
      q, k, v, Wq, Wk, Wv,
      q_hi, q_lo, k_hi, k_lo, v_b, Wq_hi, Wq_lo, Wk_hi, Wk_lo, Wv_b);

  // 2) qp & kp projections in ONE launch (z=0: q@Wq^T+bq, z=1: k@Wk^T+bk), split out
  gemm_nt<true, 0><<<dim3(F / BN, (B * S) / BM, 2), blk, 0, stream>>>(
      q_hi, q_lo, Wq_hi, Wq_lo, bq, bk, nullptr, qp_hi, qp_lo,
      B * S, F, F, NSF, NFF, NSF, 0, S);

  // 3) vp = v @ Wv^T + bv, written transposed per batch: vpT[b][g][s]
  gemm_nt<false, 1><<<dim3(F / BN, (B * S) / BM, 1), blk, 0, stream>>>(
      v_b, nullptr, Wv_b, nullptr, bv, nullptr, nullptr, vpT, nullptr,
      B * S, F, F, 0, 0, 0, 0, S);

  // 4) scores[b] = qp[b] @ kp[b]^T  (split-precision, fp32 out)
  gemm_nt<true, 2><<<dim3(S / BN, S / BM, B), blk, 0, stream>>>(
      qp_hi, qp_lo, kp_hi, kp_lo, nullptr, nullptr, nullptr, scores, nullptr,
      S, S, F, (long)S * F, (long)S * F, (long)S * S, 0, S);

  // 5) attn = softmax(scores) as bf16
  softmax_kernel<<<dim3(B * S), blk, 0, stream>>>(scores, attn, S);

  // 6) out[b] = attn[b] @ vp[b] + q[b]
  gemm_nt<false, 3><<<dim3(F / BN, S / BM, B), blk, 0, stream>>>(
      attn, nullptr, vpT, nullptr, nullptr, nullptr, q, out, nullptr,
      S, F, S, (long)S * S, (long)F * S, (long)S * F, (long)S * F, S);
}

// Round 3
// 470.491 us; speedup vs baseline: 1.1655x; 1.1113x over previous
//
#include <hip/hip_runtime.h>

typedef unsigned short u16;
typedef __bf16 bf16x8 __attribute__((ext_vector_type(8)));
typedef float f32x4 __attribute__((ext_vector_type(4)));
typedef u16 u16x8 __attribute__((ext_vector_type(8)));

union B8 { u16x8 u; bf16x8 b; };

__device__ __forceinline__ u16 f2b(float f){
  unsigned u = __float_as_uint(f);
  return (u16)((u + 0x7FFFu + ((u >> 16) & 1u)) >> 16);
}
__device__ __forceinline__ float b2f(u16 h){ return __uint_as_float(((unsigned)h) << 16); }

// ---------------- fused split ----------------
// 8 floats/thread. Dual tensors -> paired layout: per 8-k group [hi x8][lo x8].
// blocks: q[0,4096) k[4096,8192) v[8192,12288) Wq[12288,12800) Wk[12800,13312) Wv[13312,13824)
__global__ __launch_bounds__(256) void split_all_kernel(
    const float* __restrict__ q, const float* __restrict__ k, const float* __restrict__ v,
    const float* __restrict__ Wq, const float* __restrict__ Wk, const float* __restrict__ Wv,
    u16* __restrict__ q_pair, u16* __restrict__ k_pair, u16* __restrict__ v_b,
    u16* __restrict__ Wq_pair, u16* __restrict__ Wk_pair, u16* __restrict__ Wv_b)
{
  int b = blockIdx.x;
  const float* src; u16* dst; bool dual; long base;
  if      (b < 4096)  { src = q;  dst = q_pair;  dual = true;  base = b; }
  else if (b < 8192)  { src = k;  dst = k_pair;  dual = true;  base = b - 4096; }
  else if (b < 12288) { src = v;  dst = v_b;     dual = false; base = b - 8192; }
  else if (b < 12800) { src = Wq; dst = Wq_pair; dual = true;  base = b - 12288; }
  else if (b < 13312) { src = Wk; dst = Wk_pair; dual = true;  base = b - 12800; }
  else                { src = Wv; dst = Wv_b;    dual = false; base = b - 13312; }
  long i = base * 256 + threadIdx.x;   // 8-float group index
  float4 x0 = ((const float4*)src)[2 * i];
  float4 x1 = ((const float4*)src)[2 * i + 1];
  float xs[8] = {x0.x, x0.y, x0.z, x0.w, x1.x, x1.y, x1.z, x1.w};
  u16x8 h, l;
  #pragma unroll
  for (int j = 0; j < 8; j++){ h[j] = f2b(xs[j]); l[j] = f2b(xs[j] - b2f(h[j])); }
  if (dual){
    ((u16x8*)dst)[2 * i]     = h;
    ((u16x8*)dst)[2 * i + 1] = l;
  } else {
    ((u16x8*)dst)[i] = h;
  }
}

// ---------------- XCD-aware block remap ----------------
// HW maps linear block id b to XCD b%8 (round-robin). Re-decode so each XCD owns
// a contiguous z-major / y-band chunk -> per-XCD L2 working set ~8-12 MB instead
// of the whole input. Speed-only heuristic (G16-safe). Requires NB % 8 == 0.
__device__ __forceinline__ void xcd_remap(int& tx, int& ty, int& tz){
  const int GX = gridDim.x, GY = gridDim.y;
  int b  = blockIdx.x + GX * (blockIdx.y + GY * blockIdx.z);
  int NB = GX * GY * gridDim.z;
  int rank = (b & 7) * (NB >> 3) + (b >> 3);
  int pz = GX * GY;
  tz = rank / pz;
  int r = rank - tz * pz;
  ty = r / GX;
  tx = r - ty * GX;
}

// ---------------- NT GEMM: C[m][n] = sum_k A[m][k] * B[n][k] ----------------
// DUAL: A,B in paired hi|lo layout (row stride 2K u16); acc = Ah*Bh + Ah*Bl + Al*Bh
// EPI: 0 = +bias(z-select), write paired hi|lo (batched by sOb)
//      1 = +bias, write bf16 transposed per-batch: out[(m/seq)][n][m%seq]
//      2 = write fp32 C (batched by sOb)
//      3 = + residual, write fp32 C (batched)
constexpr int BM = 128, BN = 128, BK = 32;

// single path: row = 32 u16 = 64B = 4 x 16B groups, rotate-swizzle (measured 0 conflicts)
__device__ __forceinline__ int lds1_idx(int row, int g){
  return row * 32 + (((g + (row >> 1)) & 3) << 3);
}
// dual/paired path: row = 64 u16 = 128B = 8 x 16B groups; 128B stride => bank is
// column-only, so XOR-swizzle with row&7. Reads & writes: 8 lanes per 4-bank
// cluster = minimum phases, conflict-free.
__device__ __forceinline__ int lds2_idx(int row, int g){
  return row * 64 + (((g ^ (row & 7)) & 7) << 3);
}

template<bool DUAL, int EPI>
__global__ __launch_bounds__(256, 4)   // dual LDS 32KB x4 = 128KB <= 160KB
void gemm_nt(const u16* __restrict__ A, const u16* __restrict__ Bm,
             const float* __restrict__ bias, const float* __restrict__ biasB,
             const float* __restrict__ residual,
             void* __restrict__ out0,
             int M, int N, int K,
             long sAb, long sBb, long sOb, long sRb, int seq)
{
  constexpr int RW = DUAL ? 64 : 32;   // u16 per row per K-step in LDS
  __shared__ u16 lds[2][BM * RW];

  int tx, ty, tz; xcd_remap(tx, ty, tz);
  const int t = threadIdx.x;
  const int tileM = ty * BM;
  const int tileN = tx * BN;
  const long rs = DUAL ? 2L * K : (long)K;   // row stride (u16)

  const u16* gA = A  + tz * sAb + (long)tileM * rs;
  const u16* gB = Bm + tz * sBb + (long)tileN * rs;

  const int wave = t >> 6, lane = t & 63;
  const int wm = (wave >> 1) * 64, wn = (wave & 1) * 64;
  const int lr = lane & 15;       // row/col within 16x16 tile
  const int lg = lane >> 4;       // k-group (8 elems) of the fragment

  f32x4 acc[4][4] = {};

  for (int k0 = 0; k0 < K; k0 += BK){
    __syncthreads();
    if (DUAL){
      #pragma unroll
      for (int arr = 0; arr < 2; arr++){
        const u16* src = arr ? gB : gA;
        #pragma unroll
        for (int i = 0; i < 2; i++){
          int seg = t + i * 256;                 // 0..511
          int row = seg >> 2, g2 = (seg & 3) * 2;
          const u16* s = src + (long)row * rs + (long)k0 * 2 + g2 * 8;
          u16x8 a0 = *(const u16x8*)(s);
          u16x8 a1 = *(const u16x8*)(s + 8);
          *(u16x8*)&lds[arr][lds2_idx(row, g2)]     = a0;
          *(u16x8*)&lds[arr][lds2_idx(row, g2 + 1)] = a1;
        }
      }
    } else {
      #pragma unroll
      for (int arr = 0; arr < 2; arr++){
        const u16* src = arr ? gB : gA;
        #pragma unroll
        for (int i = 0; i < 2; i++){
          int seg = t + i * 256;
          int row = seg >> 2, g = seg & 3;
          *(u16x8*)&lds[arr][lds1_idx(row, g)] =
              *(const u16x8*)(src + (long)row * rs + k0 + g * 8);
        }
      }
    }
    __syncthreads();

    if (DUAL){
      B8 ah[4], al[4], bh[4], bl[4];
      #pragma unroll
      for (int mt = 0; mt < 4; mt++){
        int row = wm + mt * 16 + lr;
        ah[mt].u = *(const u16x8*)&lds[0][lds2_idx(row, lg * 2)];
        al[mt].u = *(const u16x8*)&lds[0][lds2_idx(row, lg * 2 + 1)];
      }
      #pragma unroll
      for (int nt = 0; nt < 4; nt++){
        int row = wn + nt * 16 + lr;
        bh[nt].u = *(const u16x8*)&lds[1][lds2_idx(row, lg * 2)];
        bl[nt].u = *(const u16x8*)&lds[1][lds2_idx(row, lg * 2 + 1)];
      }
      #pragma unroll
      for (int mt = 0; mt < 4; mt++){
        #pragma unroll
        for (int nt = 0; nt < 4; nt++){
          acc[mt][nt] = __builtin_amdgcn_mfma_f32_16x16x32_bf16(ah[mt].b, bh[nt].b, acc[mt][nt], 0, 0, 0);
          acc[mt][nt] = __builtin_amdgcn_mfma_f32_16x16x32_bf16(ah[mt].b, bl[nt].b, acc[mt][nt], 0, 0, 0);
          acc[mt][nt] = __builtin_amdgcn_mfma_f32_16x16x32_bf16(al[mt].b, bh[nt].b, acc[mt][nt], 0, 0, 0);
        }
      }
    } else {
      B8 af[4], bf[4];
      #pragma unroll
      for (int mt = 0; mt < 4; mt++)
        af[mt].u = *(const u16x8*)&lds[0][lds1_idx(wm + mt * 16 + lr, lg)];
      #pragma unroll
      for (int nt = 0; nt < 4; nt++)
        bf[nt].u = *(const u16x8*)&lds[1][lds1_idx(wn + nt * 16 + lr, lg)];
      #pragma unroll
      for (int mt = 0; mt < 4; mt++)
        #pragma unroll
        for (int nt = 0; nt < 4; nt++)
          acc[mt][nt] = __builtin_amdgcn_mfma_f32_16x16x32_bf16(af[mt].b, bf[nt].b, acc[mt][nt], 0, 0, 0);
    }
  }

  // epilogue: C/D layout col=lane&15, row=(lane>>4)*4+reg  [m89-verified]
  const int rq = lg * 4;
  const float* bp = (tz && biasB) ? biasB : bias;
  #pragma unroll
  for (int nt = 0; nt < 4; nt++){
    const int n = tileN + wn + nt * 16 + lr;
    const float bv = (EPI <= 1) ? bp[n] : 0.f;
    #pragma unroll
    for (int mt = 0; mt < 4; mt++){
      #pragma unroll
      for (int r = 0; r < 4; r++){
        const int m = tileM + wm + mt * 16 + rq + r;
        float val = acc[mt][nt][r] + bv;
        if (EPI == 0){
          u16 h = f2b(val);
          u16* o = (u16*)out0 + (long)tz * sOb + (long)m * 2 * N + ((n >> 3) << 4) + (n & 7);
          o[0] = h;
          o[8] = f2b(val - b2f(h));
        } else if (EPI == 1){
          long idx = (long)(m / seq) * ((long)N * seq) + (long)n * seq + (m % seq);
          ((u16*)out0)[idx] = f2b(val);
        } else if (EPI == 2){
          ((float*)out0)[(long)tz * sOb + (long)m * N + n] = val;
        } else {
          float res = residual[(long)tz * sRb + (long)m * N + n];
          ((float*)out0)[(long)tz * sOb + (long)m * N + n] = val + res;
        }
      }
    }
  }
}

// ---------------- row softmax: fp32 scores -> bf16 probs (n == 2048) ----------------
__global__ __launch_bounds__(256)
void softmax_kernel(const float* __restrict__ S, u16* __restrict__ P, int n){
  const long row = blockIdx.x;
  const float* r = S + row * (long)n;
  const int t = threadIdx.x;
  float v[8];
  float mx = -3.0e38f;
  #pragma unroll
  for (int i = 0; i < 8; i++){ v[i] = r[t + (i << 8)]; mx = fmaxf(mx, v[i]); }
  #pragma unroll
  for (int off = 32; off > 0; off >>= 1) mx = fmaxf(mx, __shfl_xor(mx, off, 64));
  __shared__ float red[8];
  const int wave = t >> 6;
  if ((t & 63) == 0) red[wave] = mx;
  __syncthreads();
  mx = fmaxf(fmaxf(red[0], red[1]), fmaxf(red[2], red[3]));
  float s = 0.f;
  #pragma unroll
  for (int i = 0; i < 8; i++){ v[i] = __expf(v[i] - mx); s += v[i]; }
  #pragma unroll
  for (int off = 32; off > 0; off >>= 1) s += __shfl_xor(s, off, 64);
  if ((t & 63) == 0) red[4 + wave] = s;
  __syncthreads();
  s = red[4] + red[5] + red[6] + red[7];
  const float inv = 1.f / s;
  u16* pr = P + row * (long)n;
  #pragma unroll
  for (int i = 0; i < 8; i++) pr[t + (i << 8)] = f2b(v[i] * inv);
}

extern "C" void kernel_launch(void* const* d_in, const int* in_sizes, int n_in,
                              void* d_out, int out_size, void* d_ws, size_t ws_size,
                              hipStream_t stream){
  (void)in_sizes; (void)n_in; (void)out_size; (void)ws_size;
  const float* q  = (const float*)d_in[0];
  const float* k  = (const float*)d_in[1];
  const float* v  = (const float*)d_in[2];
  const float* Wq = (const float*)d_in[3];
  const float* bq = (const float*)d_in[4];
  const float* Wk = (const float*)d_in[5];
  const float* bk = (const float*)d_in[6];
  const float* Wv = (const float*)d_in[7];
  const float* bv = (const float*)d_in[8];
  float* out = (float*)d_out;

  const int B = 4, S = 2048, F = 1024;
  const long NSF = (long)B * S * F;   // 8 Mi
  const long NFF = (long)F * F;       // 1 Mi
  const long NSS = (long)B * S * S;   // 16 Mi

  char* w = (char*)d_ws;
  auto alloc = [&](long bytes) -> char* {
    char* p = w; w += (bytes + 255) & ~(long)255; return p;
  };
  // persistent: qp|kp paired (contiguous for one z=2 launch), vpT   (83.9 MB)
  u16* qp_pair = (u16*)alloc(4 * NSF * 2);      // qp at 0, kp at +2*NSF
  u16* kp_pair = qp_pair + 2 * NSF;
  u16* vpT     = (u16*)alloc(NSF * 2);
  // zone2 (100.7 MB): phase-1 split inputs alias attn+scores (disjoint lifetimes)
  char* zone2 = alloc(NSS * 2 + NSS * 4);
  u16*   attn   = (u16*)zone2;                  // written by softmax (launch 5)
  float* scores = (float*)(zone2 + NSS * 2);    // written by QK^T   (launch 4)
  u16* q_pair  = (u16*)zone2;                   // phase-1, dead after launch 2/3
  u16* k_pair  = q_pair + 2 * NSF;
  u16* v_b     = k_pair + 2 * NSF;
  u16* Wq_pair = v_b + NSF;
  u16* Wk_pair = Wq_pair + 2 * NFF;
  u16* Wv_b    = Wk_pair + 2 * NFF;

  dim3 blk(256);

  // 1) split all inputs (dual tensors -> paired hi|lo)
  split_all_kernel<<<dim3(13824), blk, 0, stream>>>(
      q, k, v, Wq, Wk, Wv, q_pair, k_pair, v_b, Wq_pair, Wk_pair, Wv_b);

  // 2) qp & kp projections, one z=2 launch; paired output
  gemm_nt<true, 0><<<dim3(F / BN, (B * S) / BM, 2), blk, 0, stream>>>(
      q_pair, Wq_pair, bq, bk, nullptr, qp_pair,
      B * S, F, F, 2 * NSF, 2 * NFF, 2 * NSF, 0, S);

  // 3) vp = v @ Wv^T + bv -> vpT[b][g][s] (bf16)
  gemm_nt<false, 1><<<dim3(F / BN, (B * S) / BM, 1), blk, 0, stream>>>(
      v_b, Wv_b, bv, nullptr, nullptr, vpT,
      B * S, F, F, 0, 0, 0, 0, S);

  // 4) scores[b] = qp[b] @ kp[b]^T (fp32)
  gemm_nt<true, 2><<<dim3(S / BN, S / BM, B), blk, 0, stream>>>(
      qp_pair, kp_pair, nullptr, nullptr, nullptr, scores,
      S, S, F, (long)S * 2 * F, (long)S * 2 * F, (long)S * S, 0, S);

  // 5) attn = softmax(scores) (bf16)
  softmax_kernel<<<dim3(B * S), blk, 0, stream>>>(scores, attn, S);

  // 6) out[b] = attn[b] @ vp[b] + q[b]
  gemm_nt<false, 3><<<dim3(F / BN, S / BM, B), blk, 0, stream>>>(
      attn, vpT, nullptr, nullptr, q, out,
      S, F, S, (long)S * S, (long)F * S, (long)S * F, (long)S * F, S);
}

// Round 4
// 454.347 us; speedup vs baseline: 1.2069x; 1.0355x over previous
//
#include <hip/hip_runtime.h>

typedef unsigned short u16;
typedef __bf16 bf16x8 __attribute__((ext_vector_type(8)));
typedef float f32x4 __attribute__((ext_vector_type(4)));
typedef u16 u16x8 __attribute__((ext_vector_type(8)));

union B8 { u16x8 u; bf16x8 b; };

__device__ __forceinline__ u16 f2b(float f){
  unsigned u = __float_as_uint(f);
  return (u16)((u + 0x7FFFu + ((u >> 16) & 1u)) >> 16);
}
__device__ __forceinline__ float b2f(u16 h){ return __uint_as_float(((unsigned)h) << 16); }

// async global->LDS, 16B per lane. LDS dest is wave-uniform base + lane*16;
// global address is PER-LANE (gather) — swizzle is folded into the source address.
__device__ __forceinline__ void gload16(const u16* g, u16* l){
  __builtin_amdgcn_global_load_lds((const __attribute__((address_space(1))) void*)g,
                                   (__attribute__((address_space(3))) void*)l, 16, 0, 0);
}

// ---------------- fused split ----------------
// 8 floats/thread. Dual tensors -> paired layout: per 8-k group [hi x8][lo x8].
// blocks: q[0,4096) k[4096,8192) v[8192,12288) Wq[12288,12800) Wk[12800,13312) Wv[13312,13824)
__global__ __launch_bounds__(256) void split_all_kernel(
    const float* __restrict__ q, const float* __restrict__ k, const float* __restrict__ v,
    const float* __restrict__ Wq, const float* __restrict__ Wk, const float* __restrict__ Wv,
    u16* __restrict__ q_pair, u16* __restrict__ k_pair, u16* __restrict__ v_b,
    u16* __restrict__ Wq_pair, u16* __restrict__ Wk_pair, u16* __restrict__ Wv_b)
{
  int b = blockIdx.x;
  const float* src; u16* dst; bool dual; long base;
  if      (b < 4096)  { src = q;  dst = q_pair;  dual = true;  base = b; }
  else if (b < 8192)  { src = k;  dst = k_pair;  dual = true;  base = b - 4096; }
  else if (b < 12288) { src = v;  dst = v_b;     dual = false; base = b - 8192; }
  else if (b < 12800) { src = Wq; dst = Wq_pair; dual = true;  base = b - 12288; }
  else if (b < 13312) { src = Wk; dst = Wk_pair; dual = true;  base = b - 12800; }
  else                { src = Wv; dst = Wv_b;    dual = false; base = b - 13312; }
  long i = base * 256 + threadIdx.x;   // 8-float group index
  float4 x0 = ((const float4*)src)[2 * i];
  float4 x1 = ((const float4*)src)[2 * i + 1];
  float xs[8] = {x0.x, x0.y, x0.z, x0.w, x1.x, x1.y, x1.z, x1.w};
  u16x8 h, l;
  #pragma unroll
  for (int j = 0; j < 8; j++){ h[j] = f2b(xs[j]); l[j] = f2b(xs[j] - b2f(h[j])); }
  if (dual){
    ((u16x8*)dst)[2 * i]     = h;
    ((u16x8*)dst)[2 * i + 1] = l;
  } else {
    ((u16x8*)dst)[i] = h;
  }
}

// ---------------- XCD-aware block remap ----------------
// HW maps linear block id b to XCD b%8 (verified R3: QK^T FETCH 368->71 MB).
__device__ __forceinline__ void xcd_remap(int& tx, int& ty, int& tz){
  const int GX = gridDim.x, GY = gridDim.y;
  int b  = blockIdx.x + GX * (blockIdx.y + GY * blockIdx.z);
  int NB = GX * GY * gridDim.z;
  int rank = (b & 7) * (NB >> 3) + (b >> 3);
  int pz = GX * GY;
  tz = rank / pz;
  int r = rank - tz * pz;
  ty = r / GX;
  tx = r - ty * GX;
}

// ---------------- NT GEMM: C[m][n] = sum_k A[m][k] * B[n][k] ----------------
// DUAL: A,B in paired hi|lo layout (row stride 2K u16); acc = Ah*Bh + Ah*Bl + Al*Bh
// EPI: 0 = +bias(z-select), write paired hi|lo (batched by sOb)
//      1 = +bias, write bf16 transposed per-batch: out[(m/seq)][n][m%seq]
//      2 = write fp32 C (batched by sOb)
//      3 = + residual, write fp32 C (batched)
constexpr int BM = 128, BN = 128, BK = 32;

// single path: plain image [row][32 u16]; 64B row stride is conflict-free for
// 16x16 fragment b128 reads (every bank gets exactly 8 accesses = minimum).
__device__ __forceinline__ int lds1_idx(int row, int g){
  return row * 32 + g * 8;
}
// dual path: [row][64 u16] (8 x 16B slots); slot s of row r holds group s^(r&7).
// Fragment reads spread 16 same-lg lanes over all 8 slot groups -> min phases.
__device__ __forceinline__ int lds2_idx(int row, int g){
  return row * 64 + (((g ^ (row & 7)) & 7) << 3);
}

template<bool DUAL, int EPI>
__global__ __launch_bounds__(256, 4)   // dual LDS 32KB x4 = 128KB <= 160KB
void gemm_nt(const u16* __restrict__ A, const u16* __restrict__ Bm,
             const float* __restrict__ bias, const float* __restrict__ biasB,
             const float* __restrict__ residual,
             void* __restrict__ out0,
             int M, int N, int K,
             long sAb, long sBb, long sOb, long sRb, int seq)
{
  constexpr int RW = DUAL ? 64 : 32;   // u16 per row in LDS image
  __shared__ u16 lds[2][BM * RW];

  int tx, ty, tz; xcd_remap(tx, ty, tz);
  const int t = threadIdx.x;
  const int tileM = ty * BM;
  const int tileN = tx * BN;
  const long rs = DUAL ? 2L * K : (long)K;   // global row stride (u16)

  const u16* gA = A  + tz * sAb + (long)tileM * rs;
  const u16* gB = Bm + tz * sBb + (long)tileN * rs;

  const int wave = t >> 6, lane = t & 63;
  const int wm = (wave >> 1) * 64, wn = (wave & 1) * 64;
  const int lr = lane & 15;       // row/col within 16x16 tile
  const int lg = lane >> 4;       // k-group (8 elems) of the fragment

  // staging gather addresses (lane-constant part precomputed; advance per k-iter)
  const u16 *pa, *pb;
  long jstride;                   // global u16 stride between issues
  int  ldsbase, ldsstep, nissue, kadv;
  if (DUAL){
    const int lr8 = lane >> 3, sl = lane & 7;
    const int g = sl ^ lr8;                       // folded XOR swizzle
    pa = gA + (long)(wave * 32 + lr8) * rs + g * 8;
    pb = gB + (long)(wave * 32 + lr8) * rs + g * 8;
    jstride = 8 * rs;                             // 8 rows per issue
    ldsbase = (wave * 32) * 64; ldsstep = 8 * 64; // u16 units
    nissue = 4; kadv = 64;                        // k0*2 advance per BK
  } else {
    pa = gA + (long)(wave * 32 + (lane >> 2)) * rs + (lane & 3) * 8;
    pb = gB + (long)(wave * 32 + (lane >> 2)) * rs + (lane & 3) * 8;
    jstride = 16 * rs;                            // 16 rows per issue
    ldsbase = (wave * 32) * 32; ldsstep = 16 * 32;
    nissue = 2; kadv = 32;
  }

  f32x4 acc[4][4] = {};

  for (int k0 = 0; k0 < K; k0 += BK){
    __syncthreads();
    #pragma unroll 4
    for (int j = 0; j < nissue; j++){
      gload16(pa + j * jstride, &lds[0][ldsbase + j * ldsstep]);
      gload16(pb + j * jstride, &lds[1][ldsbase + j * ldsstep]);
    }
    pa += kadv; pb += kadv;
    __syncthreads();

    if (DUAL){
      B8 ah[4], al[4], bh[4], bl[4];
      #pragma unroll
      for (int mt = 0; mt < 4; mt++){
        int row = wm + mt * 16 + lr;
        ah[mt].u = *(const u16x8*)&lds[0][lds2_idx(row, lg * 2)];
        al[mt].u = *(const u16x8*)&lds[0][lds2_idx(row, lg * 2 + 1)];
      }
      #pragma unroll
      for (int nt = 0; nt < 4; nt++){
        int row = wn + nt * 16 + lr;
        bh[nt].u = *(const u16x8*)&lds[1][lds2_idx(row, lg * 2)];
        bl[nt].u = *(const u16x8*)&lds[1][lds2_idx(row, lg * 2 + 1)];
      }
      #pragma unroll
      for (int mt = 0; mt < 4; mt++){
        #pragma unroll
        for (int nt = 0; nt < 4; nt++){
          acc[mt][nt] = __builtin_amdgcn_mfma_f32_16x16x32_bf16(ah[mt].b, bh[nt].b, acc[mt][nt], 0, 0, 0);
          acc[mt][nt] = __builtin_amdgcn_mfma_f32_16x16x32_bf16(ah[mt].b, bl[nt].b, acc[mt][nt], 0, 0, 0);
          acc[mt][nt] = __builtin_amdgcn_mfma_f32_16x16x32_bf16(al[mt].b, bh[nt].b, acc[mt][nt], 0, 0, 0);
        }
      }
    } else {
      B8 af[4], bf[4];
      #pragma unroll
      for (int mt = 0; mt < 4; mt++)
        af[mt].u = *(const u16x8*)&lds[0][lds1_idx(wm + mt * 16 + lr, lg)];
      #pragma unroll
      for (int nt = 0; nt < 4; nt++)
        bf[nt].u = *(const u16x8*)&lds[1][lds1_idx(wn + nt * 16 + lr, lg)];
      #pragma unroll
      for (int mt = 0; mt < 4; mt++)
        #pragma unroll
        for (int nt = 0; nt < 4; nt++)
          acc[mt][nt] = __builtin_amdgcn_mfma_f32_16x16x32_bf16(af[mt].b, bf[nt].b, acc[mt][nt], 0, 0, 0);
    }
  }

  // epilogue: C/D layout col=lane&15, row=(lane>>4)*4+reg  [m89-verified]
  const int rq = lg * 4;
  const float* bp = (tz && biasB) ? biasB : bias;
  #pragma unroll
  for (int nt = 0; nt < 4; nt++){
    const int n = tileN + wn + nt * 16 + lr;
    const float bv = (EPI <= 1) ? bp[n] : 0.f;
    #pragma unroll
    for (int mt = 0; mt < 4; mt++){
      #pragma unroll
      for (int r = 0; r < 4; r++){
        const int m = tileM + wm + mt * 16 + rq + r;
        float val = acc[mt][nt][r] + bv;
        if (EPI == 0){
          u16 h = f2b(val);
          u16* o = (u16*)out0 + (long)tz * sOb + (long)m * 2 * N + ((n >> 3) << 4) + (n & 7);
          o[0] = h;
          o[8] = f2b(val - b2f(h));
        } else if (EPI == 1){
          long idx = (long)(m / seq) * ((long)N * seq) + (long)n * seq + (m % seq);
          ((u16*)out0)[idx] = f2b(val);
        } else if (EPI == 2){
          ((float*)out0)[(long)tz * sOb + (long)m * N + n] = val;
        } else {
          float res = residual[(long)tz * sRb + (long)m * N + n];
          ((float*)out0)[(long)tz * sOb + (long)m * N + n] = val + res;
        }
      }
    }
  }
}

// ---------------- row softmax: fp32 scores -> bf16 probs (n == 2048) ----------------
__global__ __launch_bounds__(256)
void softmax_kernel(const float* __restrict__ S, u16* __restrict__ P, int n){
  const long row = blockIdx.x;
  const float* r = S + row * (long)n;
  const int t = threadIdx.x;
  float v[8];
  float mx = -3.0e38f;
  #pragma unroll
  for (int i = 0; i < 8; i++){ v[i] = r[t + (i << 8)]; mx = fmaxf(mx, v[i]); }
  #pragma unroll
  for (int off = 32; off > 0; off >>= 1) mx = fmaxf(mx, __shfl_xor(mx, off, 64));
  __shared__ float red[8];
  const int wave = t >> 6;
  if ((t & 63) == 0) red[wave] = mx;
  __syncthreads();
  mx = fmaxf(fmaxf(red[0], red[1]), fmaxf(red[2], red[3]));
  float s = 0.f;
  #pragma unroll
  for (int i = 0; i < 8; i++){ v[i] = __expf(v[i] - mx); s += v[i]; }
  #pragma unroll
  for (int off = 32; off > 0; off >>= 1) s += __shfl_xor(s, off, 64);
  if ((t & 63) == 0) red[4 + wave] = s;
  __syncthreads();
  s = red[4] + red[5] + red[6] + red[7];
  const float inv = 1.f / s;
  u16* pr = P + row * (long)n;
  #pragma unroll
  for (int i = 0; i < 8; i++) pr[t + (i << 8)] = f2b(v[i] * inv);
}

extern "C" void kernel_launch(void* const* d_in, const int* in_sizes, int n_in,
                              void* d_out, int out_size, void* d_ws, size_t ws_size,
                              hipStream_t stream){
  (void)in_sizes; (void)n_in; (void)out_size; (void)ws_size;
  const float* q  = (const float*)d_in[0];
  const float* k  = (const float*)d_in[1];
  const float* v  = (const float*)d_in[2];
  const float* Wq = (const float*)d_in[3];
  const float* bq = (const float*)d_in[4];
  const float* Wk = (const float*)d_in[5];
  const float* bk = (const float*)d_in[6];
  const float* Wv = (const float*)d_in[7];
  const float* bv = (const float*)d_in[8];
  float* out = (float*)d_out;

  const int B = 4, S = 2048, F = 1024;
  const long NSF = (long)B * S * F;   // 8 Mi
  const long NFF = (long)F * F;       // 1 Mi
  const long NSS = (long)B * S * S;   // 16 Mi

  char* w = (char*)d_ws;
  auto alloc = [&](long bytes) -> char* {
    char* p = w; w += (bytes + 255) & ~(long)255; return p;
  };
  // persistent: qp|kp paired (contiguous for one z=2 launch), vpT   (83.9 MB)
  u16* qp_pair = (u16*)alloc(4 * NSF * 2);      // qp at 0, kp at +2*NSF
  u16* kp_pair = qp_pair + 2 * NSF;
  u16* vpT     = (u16*)alloc(NSF * 2);
  // zone2 (100.7 MB): phase-1 split inputs alias attn+scores (disjoint lifetimes)
  char* zone2 = alloc(NSS * 2 + NSS * 4);
  u16*   attn   = (u16*)zone2;                  // written by softmax (launch 5)
  float* scores = (float*)(zone2 + NSS * 2);    // written by QK^T   (launch 4)
  u16* q_pair  = (u16*)zone2;                   // phase-1, dead after launch 2/3
  u16* k_pair  = q_pair + 2 * NSF;
  u16* v_b     = k_pair + 2 * NSF;
  u16* Wq_pair = v_b + NSF;
  u16* Wk_pair = Wq_pair + 2 * NFF;
  u16* Wv_b    = Wk_pair + 2 * NFF;

  dim3 blk(256);

  // 1) split all inputs (dual tensors -> paired hi|lo)
  split_all_kernel<<<dim3(13824), blk, 0, stream>>>(
      q, k, v, Wq, Wk, Wv, q_pair, k_pair, v_b, Wq_pair, Wk_pair, Wv_b);

  // 2) qp & kp projections, one z=2 launch; paired output
  gemm_nt<true, 0><<<dim3(F / BN, (B * S) / BM, 2), blk, 0, stream>>>(
      q_pair, Wq_pair, bq, bk, nullptr, qp_pair,
      B * S, F, F, 2 * NSF, 2 * NFF, 2 * NSF, 0, S);

  // 3) vp = v @ Wv^T + bv -> vpT[b][g][s] (bf16)
  gemm_nt<false, 1><<<dim3(F / BN, (B * S) / BM, 1), blk, 0, stream>>>(
      v_b, Wv_b, bv, nullptr, nullptr, vpT,
      B * S, F, F, 0, 0, 0, 0, S);

  // 4) scores[b] = qp[b] @ kp[b]^T (fp32)
  gemm_nt<true, 2><<<dim3(S / BN, S / BM, B), blk, 0, stream>>>(
      qp_pair, kp_pair, nullptr, nullptr, nullptr, scores,
      S, S, F, (long)S * 2 * F, (long)S * 2 * F, (long)S * S, 0, S);

  // 5) attn = softmax(scores) (bf16)
  softmax_kernel<<<dim3(B * S), blk, 0, stream>>>(scores, attn, S);

  // 6) out[b] = attn[b] @ vp[b] + q[b]
  gemm_nt<false, 3><<<dim3(F / BN, S / BM, B), blk, 0, stream>>>(
      attn, vpT, nullptr, nullptr, q, out,
      S, F, S, (long)S * S, (long)F * S, (long)S * F, (long)S * F, S);
}